// Round 2
// baseline (40680.609 us; speedup 1.0000x reference)
//
#include <hip/hip_runtime.h>

// 2-layer LSTM (B=256,T=512,D=64,H=512) + FC, fp16 MFMA / fp32 accum.
// Grid 256 = 8 batch-groups x 32 hidden-slice blocks, 1 block/CU (LDS-bound),
// persistent per-layer kernels launched COOPERATIVELY (co-residency guaranteed)
// with flag-based producer/consumer step sync (bounded spin: cannot hang).

typedef _Float16 f16;
typedef _Float16 f16x8 __attribute__((ext_vector_type(8)));
typedef _Float16 f16x4 __attribute__((ext_vector_type(4)));
typedef float    f32x4 __attribute__((ext_vector_type(4)));

#define T_STEPS 512
#define NBATCH  256
#define DIN     64
#define NHID    512
#define NGRP    8
#define CBLK    32
#define NROWS   64   // gate rows per block: 4 gates x 16 hidden

__device__ __forceinline__ f32x4 mfma16(f16x8 a, f16x8 b, f32x4 c) {
    return __builtin_amdgcn_mfma_f32_16x16x32_f16(a, b, c, 0, 0, 0);
}

// One GEMM segment: NKS k-steps of K=32, two M-tiles (batches b..b+15, b+16..b+31).
// A-frags direct from global (16B/lane), B-frags from swizzled LDS.
// Depth-6 prefetch ring + even/odd accumulators to break MFMA dep chains.
template<int NKS>
__device__ __forceinline__ void seg(const f16* a0p, const f16* a1p,
                                    const f16* Wl, int nbase, int xm, int q8, int ks0,
                                    f32x4& e0, f32x4& o0, f32x4& e1, f32x4& o1)
{
    constexpr int PD = NKS < 6 ? NKS : 6;
    f16x8 fa0[PD], fa1[PD];
#pragma unroll
    for (int p = 0; p < PD; ++p) {
        fa0[p] = *reinterpret_cast<const f16x8*>(a0p + p * 32);
        fa1[p] = *reinterpret_cast<const f16x8*>(a1p + p * 32);
    }
#pragma unroll
    for (int s = 0; s < NKS; ++s) {
        const int sl = s % PD;
        const int idx = nbase + ((((ks0 + s) * 32) + q8) ^ xm);
        const f16x8 bf = *reinterpret_cast<const f16x8*>(&Wl[idx]);
        if (s & 1) { o0 = mfma16(fa0[sl], bf, o0); o1 = mfma16(fa1[sl], bf, o1); }
        else       { e0 = mfma16(fa0[sl], bf, e0); e1 = mfma16(fa1[sl], bf, e1); }
        if (s + PD < NKS) {
            fa0[sl] = *reinterpret_cast<const f16x8*>(a0p + (s + PD) * 32);
            fa1[sl] = *reinterpret_cast<const f16x8*>(a1p + (s + PD) * 32);
        }
    }
}

// sigmoid/tanh of own gate value, gather partner gates (i,f,g,o) via shfl_xor,
// update persistent c (in VGPRs), produce h. All 4 gate-lanes hold identical c.
__device__ __forceinline__ void act4(const f32x4 gv, const int gate,
                                     float (&cc)[4], float (&hh)[4])
{
#pragma unroll
    for (int jj = 0; jj < 4; ++jj) {
        const float v  = gv[jj];
        const float xs = (gate == 2) ? 2.0f * v : v;
        const float ee = exp2f(-1.44269504f * xs);
        const float sg = 1.0f / (1.0f + ee);
        const float a  = (gate == 2) ? (2.0f * sg - 1.0f) : sg;   // g uses tanh
        const float a1 = __shfl_xor(a, 1, 64);
        const float a2 = __shfl_xor(a, 2, 64);
        const float a3 = __shfl_xor(a, 3, 64);
        // value of gate j lives at xor-distance d = gate^j
        int d;
        float vi, vf, vg, vo;
        d = gate;     vi = d == 0 ? a : d == 1 ? a1 : d == 2 ? a2 : a3;
        d = gate ^ 1; vf = d == 0 ? a : d == 1 ? a1 : d == 2 ? a2 : a3;
        d = gate ^ 2; vg = d == 0 ? a : d == 1 ? a1 : d == 2 ? a2 : a3;
        d = gate ^ 3; vo = d == 0 ? a : d == 1 ? a1 : d == 2 ? a2 : a3;
        const float cn = vf * cc[jj] + vi * vg;
        cc[jj] = cn;
        const float e2 = exp2f(-2.88539008f * cn);   // tanh(c) = 2/(1+e^-2c)-1
        const float th = 2.0f / (1.0f + e2) - 1.0f;
        hh[jj] = vo * th;
    }
}

template<int KX, bool WSEQ, bool WLAST>
__global__ __launch_bounds__(256, 1) void lstm_layer(
    const f16*  __restrict__ in_seq,   // [B][T][KX] fp16
    const float* __restrict__ w_ih, const float* __restrict__ w_hh,
    const float* __restrict__ b_ih, const float* __restrict__ b_hh,
    f16* __restrict__ hbuf,            // [2][B][NHID] fp16 exchange (parity dbuf)
    f16* __restrict__ oseq,            // [B][T][NHID] fp16 (layer0 output) or null
    float* __restrict__ hlast,         // [B][NHID] f32 (layer1, t=T-1) or null
    unsigned* arr)                     // [NGRP][T] arrival counters (pre-zeroed)
{
    constexpr int KL = KX + NHID;
    __shared__ f16  Wl[NROWS * 1024];  // swizzled fp16 weights, 128 KiB
    __shared__ float Lbias[NROWS];

    const int tid = threadIdx.x;
    const int g   = blockIdx.x & 7;    // batch-group (XCD via round-robin)
    const int jb  = blockIdx.x >> 3;   // hidden-slice 0..31

    // ---- stage weights to LDS (fp16, XOR-swizzled), rows n = 4*hid_l + gate ----
    for (int nr = 0; nr < NROWS; ++nr) {
        const int grow = (nr & 3) * NHID + jb * 16 + (nr >> 2);
        const float* sih = w_ih + (size_t)grow * KX;
        const float* shh = w_hh + (size_t)grow * NHID;
        for (int k = tid; k < KL; k += 256) {
            const float v = (k < KX) ? sih[k] : shh[k - KX];
            Wl[nr * 1024 + (k ^ ((nr & 7) << 3))] = (f16)v;
        }
    }
    if (tid < NROWS) {
        const int grow = (tid & 3) * NHID + jb * 16 + (tid >> 2);
        Lbias[tid] = b_ih[grow] + b_hh[grow];
    }
    __syncthreads();

    const int w    = tid >> 6;          // wave 0..3
    const int l    = tid & 63;
    const int col  = l & 15;
    const int q    = l >> 4;
    const int q8   = q << 3;
    const int n    = (w << 4) | col;    // gate row 0..63
    const int gate = n & 3;
    const int hid  = jb * 16 + (n >> 2);
    const int bbase = g * CBLK;

    const float bias_n = Lbias[n];
    const int nbase = n << 10;
    const int xm    = (n & 7) << 3;

    // A-row pointers (A rows indexed by lane&15)
    const f16* px0 = in_seq + (size_t)(bbase + col) * T_STEPS * KX + q8;
    const f16* px1 = px0 + (size_t)16 * T_STEPS * KX;
    const int hoff0 = (bbase + col) * NHID + q8;
    const int hoff1 = hoff0 + 16 * NHID;

    float c0[4] = {0, 0, 0, 0}, c1[4] = {0, 0, 0, 0};

    for (int t = 0; t < T_STEPS; ++t) {
        f32x4 e0 = {bias_n, bias_n, bias_n, bias_n};
        f32x4 e1 = e0;
        f32x4 o0 = {0, 0, 0, 0}, o1 = {0, 0, 0, 0};

        // input-projection segment (independent of peers -> overlaps their tail)
        seg<KX / 32>(px0, px1, Wl, nbase, xm, q8, 0, e0, o0, e1, o1);
        px0 += KX; px1 += KX;

        if (t > 0) {
            // wait for all 128 waves of the group to have published h[t-1].
            // Relaxed polls (no per-poll cache inv), one acquire fence after.
            // Bounded spin: breaks (finite wrong answer) instead of hanging.
            unsigned* ap = arr + g * T_STEPS + (t - 1);
            unsigned spins = 0;
            while (__hip_atomic_load(ap, __ATOMIC_RELAXED, __HIP_MEMORY_SCOPE_AGENT) < 128u) {
                __builtin_amdgcn_s_sleep(2);
                if (++spins > (1u << 22)) break;
            }
            __builtin_amdgcn_fence(__ATOMIC_ACQUIRE, "agent");
            const f16* ph = hbuf + ((t - 1) & 1) * (NBATCH * NHID);
            seg<16>(ph + hoff0, ph + hoff1, Wl, nbase, xm, q8, KX / 32, e0, o0, e1, o1);
        }

        const f32x4 gv0 = e0 + o0;
        const f32x4 gv1 = e1 + o1;
        float h0v[4], h1v[4];
        act4(gv0, gate, c0, h0v);
        act4(gv1, gate, c1, h1v);

        // publish h (one lane per hid: the gate==0 lanes), D rows = batch 4q+jj
        f16* hbw = hbuf + (t & 1) * (NBATCH * NHID);
        if (gate == 0) {
#pragma unroll
            for (int jj = 0; jj < 4; ++jj) {
                int b2 = bbase + q * 4 + jj;
                f16 hv = (f16)h0v[jj];
                hbw[b2 * NHID + hid] = hv;
                if (WSEQ) oseq[((size_t)b2 * T_STEPS + t) * NHID + hid] = hv;
                if (WLAST) { if (t == T_STEPS - 1) hlast[b2 * NHID + hid] = h0v[jj]; }
                b2 += 16;
                hv = (f16)h1v[jj];
                hbw[b2 * NHID + hid] = hv;
                if (WSEQ) oseq[((size_t)b2 * T_STEPS + t) * NHID + hid] = hv;
                if (WLAST) { if (t == T_STEPS - 1) hlast[b2 * NHID + hid] = h1v[jj]; }
            }
        }
        if (l == 0)
            __hip_atomic_fetch_add(arr + g * T_STEPS + t, 1u,
                                   __ATOMIC_RELEASE, __HIP_MEMORY_SCOPE_AGENT);
    }
}

__global__ void pack_x(const float* __restrict__ xin, f16* __restrict__ xp, int n4) {
    const int i = blockIdx.x * blockDim.x + threadIdx.x;
    if (i < n4) {
        const float4 v = reinterpret_cast<const float4*>(xin)[i];
        f16x4 o;
        o[0] = (f16)v.x; o[1] = (f16)v.y; o[2] = (f16)v.z; o[3] = (f16)v.w;
        reinterpret_cast<f16x4*>(xp)[i] = o;
    }
}

__global__ void fc_kernel(const float* __restrict__ hlast, const float* __restrict__ wfc,
                          const float* __restrict__ bfc, float* __restrict__ out) {
    const int wv = threadIdx.x >> 6, l = threadIdx.x & 63;
    const int b  = blockIdx.x * 4 + wv;
    const float* hr = hlast + b * NHID;
    float s = 0.f;
#pragma unroll
    for (int j = 0; j < 8; ++j) s += hr[l + 64 * j] * wfc[l + 64 * j];
#pragma unroll
    for (int off = 32; off; off >>= 1) s += __shfl_xor(s, off, 64);
    if (l == 0) out[b] = s + bfc[0];
}

extern "C" void kernel_launch(void* const* d_in, const int* in_sizes, int n_in,
                              void* d_out, int out_size, void* d_ws, size_t ws_size,
                              hipStream_t stream) {
    const float* x    = (const float*)d_in[0];
    const float* wih0 = (const float*)d_in[1];
    const float* whh0 = (const float*)d_in[2];
    const float* bih0 = (const float*)d_in[3];
    const float* bhh0 = (const float*)d_in[4];
    const float* wih1 = (const float*)d_in[5];
    const float* whh1 = (const float*)d_in[6];
    const float* bih1 = (const float*)d_in[7];
    const float* bhh1 = (const float*)d_in[8];
    const float* wfc  = (const float*)d_in[9];
    const float* bfc  = (const float*)d_in[10];
    float* out = (float*)d_out;

    char* ws = (char*)d_ws;
    const size_t XPK_ELEMS = (size_t)NBATCH * T_STEPS * DIN;    // 8.39M
    const size_t I1_ELEMS  = (size_t)NBATCH * T_STEPS * NHID;   // 67.1M
    size_t off = 0;
    f16* xpk = (f16*)(ws + off);        off += XPK_ELEMS * 2;
    f16* i1  = (f16*)(ws + off);        off += I1_ELEMS * 2;        // 134 MB
    f16* hb0 = (f16*)(ws + off);        off += (size_t)2 * NBATCH * NHID * 2;
    f16* hb1 = (f16*)(ws + off);        off += (size_t)2 * NBATCH * NHID * 2;
    float* hlast = (float*)(ws + off);  off += (size_t)NBATCH * NHID * 4;
    unsigned* arr0 = (unsigned*)(ws + off); off += (size_t)NGRP * T_STEPS * 4;
    unsigned* arr1 = (unsigned*)(ws + off); off += (size_t)NGRP * T_STEPS * 4;

    // counters must be zero every call (graph replays!)
    hipMemsetAsync(arr0, 0, (size_t)2 * NGRP * T_STEPS * 4, stream);

    pack_x<<<(int)((XPK_ELEMS / 4 + 255) / 256), 256, 0, stream>>>(x, xpk, (int)(XPK_ELEMS / 4));

    // cooperative launches: guarantees all 256 blocks co-resident, so the
    // per-group flag sync has hardware-guaranteed forward progress.
    {
        const f16* in0 = xpk;
        f16* oseq0 = i1; float* hl0 = nullptr;
        void* a0[] = { (void*)&in0, (void*)&wih0, (void*)&whh0, (void*)&bih0,
                       (void*)&bhh0, (void*)&hb0, (void*)&oseq0, (void*)&hl0,
                       (void*)&arr0 };
        hipLaunchCooperativeKernel(lstm_layer<DIN, true, false>,
                                   dim3(256), dim3(256), a0, 0, stream);
    }
    {
        const f16* in1 = i1;
        f16* oseq1 = nullptr; float* hl1 = hlast;
        void* a1[] = { (void*)&in1, (void*)&wih1, (void*)&whh1, (void*)&bih1,
                       (void*)&bhh1, (void*)&hb1, (void*)&oseq1, (void*)&hl1,
                       (void*)&arr1 };
        hipLaunchCooperativeKernel(lstm_layer<NHID, false, true>,
                                   dim3(256), dim3(256), a1, 0, stream);
    }

    fc_kernel<<<64, 256, 0, stream>>>(hlast, wfc, bfc, out);
}

// Round 3
// 12753.963 us; speedup vs baseline: 3.1896x; 3.1896x over previous
//
#include <hip/hip_runtime.h>

// 2-layer LSTM (B=256,T=512,D=64,H=512) + FC, fp16 MFMA / fp32 accum.
// Grid 256 = 8 batch-groups x 32 hidden-slice blocks, 1 block/CU (LDS-bound),
// cooperative launch. Step handoff: coalesced sc1 (IF write-through) h-stores,
// per-producer flags (no RMW contention), sc1 h-loads (no cache-wide fences).

typedef _Float16 f16;
typedef _Float16 f16x8 __attribute__((ext_vector_type(8)));
typedef _Float16 f16x4 __attribute__((ext_vector_type(4)));
typedef float    f32x4 __attribute__((ext_vector_type(4)));

#define T_STEPS 512
#define NBATCH  256
#define DIN     64
#define NHID    512
#define NGRP    8
#define CBLK    32
#define NROWS   64   // gate rows per block: 4 gates x 16 hidden

__device__ __forceinline__ f32x4 mfma16(f16x8 a, f16x8 b, f32x4 c) {
    return __builtin_amdgcn_mfma_f32_16x16x32_f16(a, b, c, 0, 0, 0);
}

// A-frag load: plain cached (x path) or coherence-point bypass (h path).
template<bool BYP>
__device__ __forceinline__ f16x8 ldA(const f16* p) {
    if constexpr (!BYP) {
        return *reinterpret_cast<const f16x8*>(p);
    } else {
        union { unsigned long long u[2]; f16x8 v; } r;
        const unsigned long long* q = reinterpret_cast<const unsigned long long*>(p);
        r.u[0] = __hip_atomic_load(q,     __ATOMIC_RELAXED, __HIP_MEMORY_SCOPE_AGENT);
        r.u[1] = __hip_atomic_load(q + 1, __ATOMIC_RELAXED, __HIP_MEMORY_SCOPE_AGENT);
        return r.v;
    }
}

// One GEMM segment: NKS k-steps of K=32, two M-tiles (batches b..b+15, b+16..b+31).
// A-frags direct from global, B-frags from swizzled LDS.
// Depth-8 prefetch ring + even/odd accumulators to break MFMA dep chains.
template<int NKS, bool BYP>
__device__ __forceinline__ void seg(const f16* a0p, const f16* a1p,
                                    const f16* Wl, int nbase, int xm, int q8, int ks0,
                                    f32x4& e0, f32x4& o0, f32x4& e1, f32x4& o1)
{
    constexpr int PD = NKS < 8 ? NKS : 8;
    f16x8 fa0[PD], fa1[PD];
#pragma unroll
    for (int p = 0; p < PD; ++p) {
        fa0[p] = ldA<BYP>(a0p + p * 32);
        fa1[p] = ldA<BYP>(a1p + p * 32);
    }
#pragma unroll
    for (int s = 0; s < NKS; ++s) {
        const int sl = s % PD;
        const int idx = nbase + ((((ks0 + s) * 32) + q8) ^ xm);
        const f16x8 bf = *reinterpret_cast<const f16x8*>(&Wl[idx]);
        if (s & 1) { o0 = mfma16(fa0[sl], bf, o0); o1 = mfma16(fa1[sl], bf, o1); }
        else       { e0 = mfma16(fa0[sl], bf, e0); e1 = mfma16(fa1[sl], bf, e1); }
        if (s + PD < NKS) {
            fa0[sl] = ldA<BYP>(a0p + (s + PD) * 32);
            fa1[sl] = ldA<BYP>(a1p + (s + PD) * 32);
        }
    }
}

// sigmoid/tanh of own gate value, gather partner gates (i,f,g,o) via shfl_xor,
// update persistent c (in VGPRs), produce h. All 4 gate-lanes hold identical c.
__device__ __forceinline__ void act4(const f32x4 gv, const int gate,
                                     float (&cc)[4], float (&hh)[4])
{
#pragma unroll
    for (int jj = 0; jj < 4; ++jj) {
        const float v  = gv[jj];
        const float xs = (gate == 2) ? 2.0f * v : v;
        const float ee = exp2f(-1.44269504f * xs);
        const float sg = 1.0f / (1.0f + ee);
        const float a  = (gate == 2) ? (2.0f * sg - 1.0f) : sg;   // g uses tanh
        const float a1 = __shfl_xor(a, 1, 64);
        const float a2 = __shfl_xor(a, 2, 64);
        const float a3 = __shfl_xor(a, 3, 64);
        int d;
        float vi, vf, vg, vo;
        d = gate;     vi = d == 0 ? a : d == 1 ? a1 : d == 2 ? a2 : a3;
        d = gate ^ 1; vf = d == 0 ? a : d == 1 ? a1 : d == 2 ? a2 : a3;
        d = gate ^ 2; vg = d == 0 ? a : d == 1 ? a1 : d == 2 ? a2 : a3;
        d = gate ^ 3; vo = d == 0 ? a : d == 1 ? a1 : d == 2 ? a2 : a3;
        const float cn = vf * cc[jj] + vi * vg;
        cc[jj] = cn;
        const float e2 = exp2f(-2.88539008f * cn);   // tanh(c) = 2/(1+e^-2c)-1
        const float th = 2.0f / (1.0f + e2) - 1.0f;
        hh[jj] = vo * th;
    }
}

template<int KX, bool WSEQ, bool WLAST>
__global__ __launch_bounds__(256, 1) void lstm_layer(
    const f16*  __restrict__ in_seq,   // [B][T][KX] fp16
    const float* __restrict__ w_ih, const float* __restrict__ w_hh,
    const float* __restrict__ b_ih, const float* __restrict__ b_hh,
    f16* __restrict__ hbuf,            // [2][B][NHID] fp16 exchange (parity dbuf)
    f16* __restrict__ oseq,            // [B][T][NHID] fp16 (layer0 output) or null
    float* __restrict__ hlast,         // [B][NHID] f32 (layer1, t=T-1) or null
    unsigned* flags)                   // [NGRP][CBLK][T] per-producer flags (pre-zeroed)
{
    constexpr int KL = KX + NHID;
    __shared__ f16  Wl[NROWS * 1024];  // swizzled fp16 weights, 128 KiB
    __shared__ f16  hstage[CBLK * 16]; // 32x16 h tile for coalesced publish
    __shared__ float Lbias[NROWS];

    const int tid = threadIdx.x;
    const int g   = blockIdx.x & 7;    // batch-group (XCD round-robin)
    const int jb  = blockIdx.x >> 3;   // hidden-slice 0..31

    // ---- stage weights to LDS (fp16, XOR-swizzled), rows n = 4*hid_l + gate ----
    for (int nr = 0; nr < NROWS; ++nr) {
        const int grow = (nr & 3) * NHID + jb * 16 + (nr >> 2);
        const float* sih = w_ih + (size_t)grow * KX;
        const float* shh = w_hh + (size_t)grow * NHID;
        for (int k = tid; k < KL; k += 256) {
            const float v = (k < KX) ? sih[k] : shh[k - KX];
            Wl[nr * 1024 + (k ^ ((nr & 7) << 3))] = (f16)v;
        }
    }
    if (tid < NROWS) {
        const int grow = (tid & 3) * NHID + jb * 16 + (tid >> 2);
        Lbias[tid] = b_ih[grow] + b_hh[grow];
    }
    __syncthreads();

    const int w    = tid >> 6;          // wave 0..3
    const int l    = tid & 63;
    const int col  = l & 15;
    const int q    = l >> 4;
    const int q8   = q << 3;
    const int n    = (w << 4) | col;    // gate row 0..63
    const int gate = n & 3;
    const int hl   = n >> 2;            // local hid 0..15
    const int bbase = g * CBLK;

    const float bias_n = Lbias[n];
    const int nbase = n << 10;
    const int xm    = (n & 7) << 3;

    // A-row pointers (A rows indexed by lane&15)
    const f16* px0 = in_seq + (size_t)(bbase + col) * T_STEPS * KX + q8;
    const f16* px1 = px0 + (size_t)16 * T_STEPS * KX;
    const int hoff0 = (bbase + col) * NHID + q8;
    const int hoff1 = hoff0 + 16 * NHID;

    float c0[4] = {0, 0, 0, 0}, c1[4] = {0, 0, 0, 0};

    for (int t = 0; t < T_STEPS; ++t) {
        f32x4 e0 = {bias_n, bias_n, bias_n, bias_n};
        f32x4 e1 = e0;
        f32x4 o0 = {0, 0, 0, 0}, o1 = {0, 0, 0, 0};

        // input-projection segment (independent of peers -> overlaps their tail)
        seg<KX / 32, false>(px0, px1, Wl, nbase, xm, q8, 0, e0, o0, e1, o1);
        px0 += KX; px1 += KX;

        if (t > 0) {
            // wave-parallel poll of the 32 per-producer flags (relaxed, sc1).
            // Bounded: breaks (finite wrong answer) instead of wedging the queue.
            const unsigned* fb = flags + ((size_t)(g * CBLK) * T_STEPS) + (t - 1);
            unsigned spins = 0;
            for (;;) {
                unsigned v = 1u;
                if (l < CBLK)
                    v = __hip_atomic_load(fb + (size_t)l * T_STEPS,
                                          __ATOMIC_RELAXED, __HIP_MEMORY_SCOPE_AGENT);
                if (__all(v != 0)) break;
                __builtin_amdgcn_s_sleep(2);
                if (++spins > (1u << 16)) break;
            }
            asm volatile("" ::: "memory");   // keep h-loads below the poll
            const f16* ph = hbuf + ((t - 1) & 1) * (NBATCH * NHID);
            seg<16, true>(ph + hoff0, ph + hoff1, Wl, nbase, xm, q8, KX / 32,
                          e0, o0, e1, o1);
        }

        const f32x4 gv0 = e0 + o0;
        const f32x4 gv1 = e1 + o1;
        float h0v[4], h1v[4];
        act4(gv0, gate, c0, h0v);
        act4(gv1, gate, c1, h1v);

        // ---- publish: stage 32x16 tile in LDS, wave0 writes coalesced 16B ----
        if (gate == 0) {
#pragma unroll
            for (int jj = 0; jj < 4; ++jj) {
                hstage[(q * 4 + jj) * 16 + hl]        = (f16)h0v[jj];
                hstage[(16 + q * 4 + jj) * 16 + hl]   = (f16)h1v[jj];
            }
        }
        if (WLAST && t == T_STEPS - 1 && gate == 0) {
#pragma unroll
            for (int jj = 0; jj < 4; ++jj) {
                hlast[(bbase + q * 4 + jj) * NHID + jb * 16 + hl]      = h0v[jj];
                hlast[(bbase + 16 + q * 4 + jj) * NHID + jb * 16 + hl] = h1v[jj];
            }
        }
        __syncthreads();
        if (tid < 64) {
            const int b = tid >> 1, half = tid & 1;
            union { unsigned long long u[2]; f16x8 v; } pk;
            pk.v = *reinterpret_cast<const f16x8*>(&hstage[b * 16 + half * 8]);
            f16* dst = hbuf + (t & 1) * (NBATCH * NHID)
                     + (bbase + b) * NHID + jb * 16 + half * 8;
            unsigned long long* d64 = reinterpret_cast<unsigned long long*>(dst);
            __hip_atomic_store(d64,     pk.u[0], __ATOMIC_RELAXED, __HIP_MEMORY_SCOPE_AGENT);
            __hip_atomic_store(d64 + 1, pk.u[1], __ATOMIC_RELAXED, __HIP_MEMORY_SCOPE_AGENT);
            if (WSEQ) {
                f16* od = oseq + ((size_t)(bbase + b) * T_STEPS + t) * NHID
                        + jb * 16 + half * 8;
                *reinterpret_cast<f16x8*>(od) = pk.v;    // plain cached store
            }
        }
        if (tid == 0) {
            // drain this wave's h-stores to the coherence point, then flag.
            asm volatile("s_waitcnt vmcnt(0)" ::: "memory");
            __hip_atomic_store(&flags[((size_t)(g * CBLK + jb)) * T_STEPS + t], 1u,
                               __ATOMIC_RELAXED, __HIP_MEMORY_SCOPE_AGENT);
        }
    }
}

__global__ void pack_x(const float* __restrict__ xin, f16* __restrict__ xp, int n4) {
    const int i = blockIdx.x * blockDim.x + threadIdx.x;
    if (i < n4) {
        const float4 v = reinterpret_cast<const float4*>(xin)[i];
        f16x4 o;
        o[0] = (f16)v.x; o[1] = (f16)v.y; o[2] = (f16)v.z; o[3] = (f16)v.w;
        reinterpret_cast<f16x4*>(xp)[i] = o;
    }
}

__global__ void fc_kernel(const float* __restrict__ hlast, const float* __restrict__ wfc,
                          const float* __restrict__ bfc, float* __restrict__ out) {
    const int wv = threadIdx.x >> 6, l = threadIdx.x & 63;
    const int b  = blockIdx.x * 4 + wv;
    const float* hr = hlast + b * NHID;
    float s = 0.f;
#pragma unroll
    for (int j = 0; j < 8; ++j) s += hr[l + 64 * j] * wfc[l + 64 * j];
#pragma unroll
    for (int off = 32; off; off >>= 1) s += __shfl_xor(s, off, 64);
    if (l == 0) out[b] = s + bfc[0];
}

extern "C" void kernel_launch(void* const* d_in, const int* in_sizes, int n_in,
                              void* d_out, int out_size, void* d_ws, size_t ws_size,
                              hipStream_t stream) {
    const float* x    = (const float*)d_in[0];
    const float* wih0 = (const float*)d_in[1];
    const float* whh0 = (const float*)d_in[2];
    const float* bih0 = (const float*)d_in[3];
    const float* bhh0 = (const float*)d_in[4];
    const float* wih1 = (const float*)d_in[5];
    const float* whh1 = (const float*)d_in[6];
    const float* bih1 = (const float*)d_in[7];
    const float* bhh1 = (const float*)d_in[8];
    const float* wfc  = (const float*)d_in[9];
    const float* bfc  = (const float*)d_in[10];
    float* out = (float*)d_out;

    char* ws = (char*)d_ws;
    const size_t XPK_ELEMS = (size_t)NBATCH * T_STEPS * DIN;    // 8.39M
    const size_t I1_ELEMS  = (size_t)NBATCH * T_STEPS * NHID;   // 67.1M
    const size_t FLAG_ELEMS = (size_t)NGRP * CBLK * T_STEPS;    // 131072
    size_t off = 0;
    f16* xpk = (f16*)(ws + off);        off += XPK_ELEMS * 2;
    f16* i1  = (f16*)(ws + off);        off += I1_ELEMS * 2;        // 134 MB
    f16* hb0 = (f16*)(ws + off);        off += (size_t)2 * NBATCH * NHID * 2;
    f16* hb1 = (f16*)(ws + off);        off += (size_t)2 * NBATCH * NHID * 2;
    float* hlast = (float*)(ws + off);  off += (size_t)NBATCH * NHID * 4;
    unsigned* flg0 = (unsigned*)(ws + off); off += FLAG_ELEMS * 4;
    unsigned* flg1 = (unsigned*)(ws + off); off += FLAG_ELEMS * 4;

    // flags must be zero every call (graph replays!)
    hipMemsetAsync(flg0, 0, 2 * FLAG_ELEMS * 4, stream);

    pack_x<<<(int)((XPK_ELEMS / 4 + 255) / 256), 256, 0, stream>>>(x, xpk, (int)(XPK_ELEMS / 4));

    // cooperative launches: all 256 blocks co-resident -> flag sync has
    // hardware-guaranteed forward progress.
    {
        const f16* in0 = xpk;
        f16* oseq0 = i1; float* hl0 = nullptr;
        void* a0[] = { (void*)&in0, (void*)&wih0, (void*)&whh0, (void*)&bih0,
                       (void*)&bhh0, (void*)&hb0, (void*)&oseq0, (void*)&hl0,
                       (void*)&flg0 };
        hipLaunchCooperativeKernel(lstm_layer<DIN, true, false>,
                                   dim3(256), dim3(256), a0, 0, stream);
    }
    {
        const f16* in1 = i1;
        f16* oseq1 = nullptr; float* hl1 = hlast;
        void* a1[] = { (void*)&in1, (void*)&wih1, (void*)&whh1, (void*)&bih1,
                       (void*)&bhh1, (void*)&hb1, (void*)&oseq1, (void*)&hl1,
                       (void*)&flg1 };
        hipLaunchCooperativeKernel(lstm_layer<NHID, false, true>,
                                   dim3(256), dim3(256), a1, 0, stream);
    }

    fc_kernel<<<64, 256, 0, stream>>>(hlast, wfc, bfc, out);
}